// Round 6
// baseline (8154.333 us; speedup 1.0000x reference)
//
#include <hip/hip_runtime.h>
#include <cstdint>

typedef unsigned int u32;
typedef unsigned long long u64;

#define BATCH 8
#define H 1024
#define W 1024
#define HW (H*W)
#define NPIX (BATCH*HW)
#define KTOP 2048
#define NBIN 8192
#define SELCAP 4096

#define CAPP (1<<18)          // robust-pass peaks per batch
#define CAPC (1<<17)          // uncertain pixels per batch
#define CAPK ((1<<18)+(1<<17))// keys per batch

// margins (f32 pipeline vs f64 truth): conv err <= ~1e-4 worst-case,
// 9-sum err <= ~1.8e-3 worst-case -> delta9 = 4e-3 (2.2x), deltaV = 1e-3 (10x)
#define D9 4e-3f
#define DV 1e-3f

// ws layout (bytes)
#define OFF_MISC 0                         // u32[32]: pass[8], chk[8], cc[8], thresh[8]
#define OFF_PASS 4096                      // u32[8][CAPP]  = 8 MB
#define OFF_CHK  (OFF_PASS + 8*CAPP*4)     // u32[8][CAPC]  = 4 MB
#define OFF_KEY  (OFF_CHK  + 8*CAPC*4)     // u64[8][CAPK]  = 24 MB

// ---------------- f64 dilated conv + relu (IDENTICAL to rounds 3-5) ----------------
__device__ __forceinline__ double conv_resp_f64(
    const float* __restrict__ in, const float* __restrict__ wc,
    const float* __restrict__ wsw, int b, int y, int x)
{
  const float* base = in + (size_t)b * 3 * HW;
  const float* Sp = base;
  const float* Cp = base + HW;
  double resp = 0.0;
  const int dil[3] = {1, 4, 16};
  #pragma unroll
  for (int di = 0; di < 3; ++di) {
    int d = dil[di];
    double ac = 0.0, as = 0.0;
    #pragma unroll
    for (int ky = 0; ky < 3; ++ky) {
      int yy = y + (ky - 1) * d;
      bool yok = ((unsigned)yy < (unsigned)H);
      #pragma unroll
      for (int kx = 0; kx < 3; ++kx) {
        int xx = x + (kx - 1) * d;
        bool ok = yok && ((unsigned)xx < (unsigned)W);
        double a  = ok ? (double)Cp[yy * W + xx] : 0.0;
        double s2 = ok ? (double)Sp[yy * W + xx] : 0.0;
        ac = fma(a,  (double)wc[di * 9 + ky * 3 + kx], ac);
        as = fma(s2, (double)wsw[di * 9 + ky * 3 + kx], as);
      }
    }
    resp += ac;
    resp += as;
  }
  return resp > 0.0 ? resp : 0.0;
}

__device__ __forceinline__ u64 make_key(double val, int p) {
  u64 dbits = __double_as_longlong(val);
  return (dbits & ~0xFFFFFull) | (u64)((~(u32)p) & 0xFFFFFu);
}

// ---------------- f32 conv (guarded / interior) ----------------
template<bool GUARD>
__device__ __forceinline__ float conv_f32(
    const float* __restrict__ Sp, const float* __restrict__ Cp,
    const float* __restrict__ wc, const float* __restrict__ wsw, int y, int x)
{
  float resp = 0.f;
  #pragma unroll
  for (int di = 0; di < 3; ++di) {
    const int d = (di == 0) ? 1 : (di == 1) ? 4 : 16;
    float ac = 0.f, as = 0.f;
    #pragma unroll
    for (int ky = 0; ky < 3; ++ky) {
      int yy = y + (ky - 1) * d;
      bool yok = !GUARD || ((unsigned)yy < (unsigned)H);
      #pragma unroll
      for (int kx = 0; kx < 3; ++kx) {
        int xx = x + (kx - 1) * d;
        bool ok = yok && (!GUARD || ((unsigned)xx < (unsigned)W));
        float a  = ok ? Cp[yy * W + xx] : 0.f;
        float s2 = ok ? Sp[yy * W + xx] : 0.f;
        ac = fmaf(a,  wc[di * 9 + ky * 3 + kx], ac);
        as = fmaf(s2, wsw[di * 9 + ky * 3 + kx], as);
      }
    }
    resp += ac;
    resp += as;
  }
  return resp;
}

// ---------------- kernel 1: elementwise outputs + f32 conv ----------------
__global__ __launch_bounds__(256) void conv32_kernel(
    const float* __restrict__ in, const float* __restrict__ wc,
    const float* __restrict__ wsw, float* __restrict__ out0,
    float* __restrict__ convr)
{
  int gid = blockIdx.x * 256 + threadIdx.x;
  int b = gid >> 20;
  int p = gid & (HW - 1);
  int y = p >> 10;
  int x = p & (W - 1);

  const float* base = in + (size_t)b * 3 * HW;
  const float* Sp = base;
  const float* Cp = base + HW;
  float sv = Sp[p];
  float cv = Cp[p];
  float rv = base[2 * HW + p];
  float* ob = out0 + (size_t)b * 3 * HW;
  ob[p] = sv;
  ob[HW + p] = cv;
  ob[2 * HW + p] = expf(rv) - 1.0f;

  bool interior = (x >= 16) && (x <= W - 17) && (y >= 16) && (y <= H - 17);
  float r = interior ? conv_f32<false>(Sp, Cp, wc, wsw, y, x)
                     : conv_f32<true >(Sp, Cp, wc, wsw, y, x);
  convr[(size_t)b * HW + p] = fmaxf(r, 0.f);
}

// ---------------- kernel 2: f32 margin screen -> passlist / checklist ----------------
__global__ __launch_bounds__(256) void screen_kernel(
    const float* __restrict__ convr, u32* __restrict__ passlist,
    u32* __restrict__ checklist, u32* __restrict__ misc)
{
  int gid = blockIdx.x * 256 + threadIdx.x;
  int b = gid >> 20;
  int p = gid & (HW - 1);
  int y = p >> 10;
  int x = p & (W - 1);
  if (y < 5 || y > H - 6 || x < 5 || x > W - 6) return;

  const float* c0 = convr + (size_t)b * HW + p - 2 * W - 2;
  float cs0[5], cs1[5], cs2[5], val = 0.f;
  #pragma unroll
  for (int j = 0; j < 5; ++j) {
    float v0 = c0[j];
    float v1 = c0[W + j];
    float v2 = c0[2 * W + j];
    float v3 = c0[3 * W + j];
    float v4 = c0[4 * W + j];
    cs0[j] = v0 + v1 + v2;
    cs1[j] = v1 + v2 + v3;
    cs2[j] = v2 + v3 + v4;
    if (j == 2) val = v2;
  }
  float sc9 = cs1[1] + cs1[2] + cs1[3];
  float n00 = cs0[0] + cs0[1] + cs0[2], n01 = cs0[1] + cs0[2] + cs0[3], n02 = cs0[2] + cs0[3] + cs0[4];
  float n10 = cs1[0] + cs1[1] + cs1[2], n12 = cs1[2] + cs1[3] + cs1[4];
  float n20 = cs2[0] + cs2[1] + cs2[2], n21 = cs2[1] + cs2[2] + cs2[3], n22 = cs2[2] + cs2[3] + cs2[4];
  float m9 = fmaxf(fmaxf(fmaxf(n00, n01), fmaxf(n02, n10)),
                   fmaxf(fmaxf(n12, n20), fmaxf(n21, n22)));

  if ((sc9 < 0.9f - D9) || (sc9 < m9 - D9) || (val < 0.1f - DV)) return;

  bool pass = (sc9 > 0.9f + D9) && (sc9 >= m9 + D9) && (val > 0.1f + DV);
  if (pass) {
    u32 pos = atomicAdd(&misc[b], 1u);
    if (pos < CAPP) passlist[(size_t)b * CAPP + pos] = (u32)p;
  } else {
    u32 pos = atomicAdd(&misc[8 + b], 1u);
    if (pos < CAPC) checklist[(size_t)b * CAPC + pos] = (u32)p;
  }
}

// ---------------- kernel 3: f64 keys for robust-pass peaks ----------------
__global__ __launch_bounds__(256) void keygen_kernel(
    const float* __restrict__ in, const float* __restrict__ wc,
    const float* __restrict__ wsw, const u32* __restrict__ passlist,
    const u32* __restrict__ misc, u64* __restrict__ keylist)
{
  int gtid = blockIdx.x * 256 + threadIdx.x;
  int gsz = gridDim.x * 256;
  for (int b = 0; b < BATCH; ++b) {
    int np = (int)min(misc[b], (u32)CAPP);
    for (int i = gtid; i < np; i += gsz) {
      int p = (int)passlist[(size_t)b * CAPP + i];
      double v = conv_resp_f64(in, wc, wsw, b, p >> 10, p & (W - 1));
      keylist[(size_t)b * CAPK + i] = make_key(v, p);
    }
  }
}

// ---------------- kernel 4: exact f64 recheck of uncertain pixels ----------------
__global__ __launch_bounds__(256) void recheck_kernel(
    const float* __restrict__ in, const float* __restrict__ wc,
    const float* __restrict__ wsw, const u32* __restrict__ checklist,
    u32* __restrict__ misc, u64* __restrict__ keylist)
{
  int gtid = blockIdx.x * 256 + threadIdx.x;
  int gsz = gridDim.x * 256;
  for (int b = 0; b < BATCH; ++b) {
    int nc = (int)min(misc[8 + b], (u32)CAPC);
    int base = (int)min(misc[b], (u32)CAPP);
    for (int i = gtid; i < nc; i += gsz) {
      int p = (int)checklist[(size_t)b * CAPC + i];
      int y = p >> 10, x = p & (W - 1);

      double cs0[5], cs1[5], cs2[5], val = 0.0;
      #pragma unroll
      for (int jc = 0; jc < 5; ++jc) {
        double v0 = conv_resp_f64(in, wc, wsw, b, y - 2, x + jc - 2);
        double v1 = conv_resp_f64(in, wc, wsw, b, y - 1, x + jc - 2);
        double v2 = conv_resp_f64(in, wc, wsw, b, y,     x + jc - 2);
        double v3 = conv_resp_f64(in, wc, wsw, b, y + 1, x + jc - 2);
        double v4 = conv_resp_f64(in, wc, wsw, b, y + 2, x + jc - 2);
        cs0[jc] = v0 + v1 + v2;
        cs1[jc] = v1 + v2 + v3;
        cs2[jc] = v2 + v3 + v4;
        if (jc == 2) val = v2;
      }
      double sc = (cs1[1] + cs1[2] + cs1[3]) * (1.0 / 9.0);
      if (!(sc > 0.1)) continue;
      bool pk = true;
      #pragma unroll
      for (int j = 0; j < 3; ++j) {
        pk = pk && (sc >= (cs0[j] + cs0[j + 1] + cs0[j + 2]) * (1.0 / 9.0));
        pk = pk && (sc >= (cs2[j] + cs2[j + 1] + cs2[j + 2]) * (1.0 / 9.0));
      }
      pk = pk && (sc >= (cs1[0] + cs1[1] + cs1[2]) * (1.0 / 9.0));
      pk = pk && (sc >= (cs1[2] + cs1[3] + cs1[4]) * (1.0 / 9.0));
      if (!pk) continue;
      if (!(val > 0.1)) continue;

      u32 pos = atomicAdd(&misc[16 + b], 1u);
      if (base + (int)pos < CAPK)
        keylist[(size_t)b * CAPK + base + pos] = make_key(val, p);
    }
  }
}

// ---------------- kernel 5: 2-level radix select -> threshold ----------------
__global__ __launch_bounds__(1024) void select_kernel(
    const u64* __restrict__ keylist, u32* __restrict__ misc)
{
  __shared__ u32 sfx[NBIN];
  __shared__ u32 sh_t1, sh_ab;
  int b = blockIdx.x;
  int tid = threadIdx.x;
  int np = (int)min(misc[b], (u32)CAPP);
  int nc = (int)min(misc[16 + b], (u32)(CAPK - np));
  int N = np + nc;
  const u64* L = keylist + (size_t)b * CAPK;
  u32* thresh = misc + 24;

  #pragma unroll
  for (int k = 0; k < 8; ++k) sfx[tid * 8 + k] = 0;
  __syncthreads();
  for (int i = tid; i < N; i += 1024)
    atomicAdd(&sfx[(u32)((L[i] >> 51) & 0x1FFF)], 1u);
  __syncthreads();

  for (int off = 1; off < NBIN; off <<= 1) {
    u32 t[8];
    #pragma unroll
    for (int k = 0; k < 8; ++k) {
      int i = tid * 8 + k;
      t[k] = (i + off < NBIN) ? sfx[i + off] : 0u;
    }
    __syncthreads();
    #pragma unroll
    for (int k = 0; k < 8; ++k) sfx[tid * 8 + k] += t[k];
    __syncthreads();
  }

  u32 total = sfx[0];
  if (total <= KTOP) { if (tid == 0) thresh[b] = 0u; return; }

  #pragma unroll
  for (int k = 0; k < 8; ++k) {
    int i = tid * 8 + k;
    u32 s = sfx[i];
    u32 nxt = (i + 1 < NBIN) ? sfx[i + 1] : 0u;
    if (s >= KTOP && nxt < KTOP) { sh_t1 = (u32)i; sh_ab = nxt; }
  }
  __syncthreads();
  u32 t1 = sh_t1, ab = sh_ab;
  __syncthreads();

  #pragma unroll
  for (int k = 0; k < 8; ++k) sfx[tid * 8 + k] = 0;
  __syncthreads();
  for (int i = tid; i < N; i += 1024) {
    u64 kk = L[i];
    if ((u32)((kk >> 51) & 0x1FFF) == t1)
      atomicAdd(&sfx[(u32)((kk >> 38) & 0x1FFF)], 1u);
  }
  __syncthreads();

  for (int off = 1; off < NBIN; off <<= 1) {
    u32 t[8];
    #pragma unroll
    for (int k = 0; k < 8; ++k) {
      int i = tid * 8 + k;
      t[k] = (i + off < NBIN) ? sfx[i + off] : 0u;
    }
    __syncthreads();
    #pragma unroll
    for (int k = 0; k < 8; ++k) sfx[tid * 8 + k] += t[k];
    __syncthreads();
  }

  #pragma unroll
  for (int k = 0; k < 8; ++k) {
    int i = tid * 8 + k;
    u32 s = ab + sfx[i];
    u32 nxt = ab + ((i + 1 < NBIN) ? sfx[i + 1] : 0u);
    if (s >= KTOP && nxt < KTOP) thresh[b] = (t1 << 13) | (u32)i;
  }
}

// ---------------- kernel 6: compact -> bitonic sort -> center_pred ----------------
__global__ __launch_bounds__(1024) void sort_out_kernel(
    const u64* __restrict__ keylist, const u32* __restrict__ misc,
    const float* __restrict__ convr, float* __restrict__ center)
{
  __shared__ u64 sk[SELCAP];
  __shared__ u32 scnt;
  int b = blockIdx.x;
  int tid = threadIdx.x;
  if (tid == 0) scnt = 0;
  for (int i = tid; i < SELCAP; i += 1024) sk[i] = 0ULL;
  __syncthreads();

  int np = (int)min(misc[b], (u32)CAPP);
  int nc = (int)min(misc[16 + b], (u32)(CAPK - np));
  int N = np + nc;
  u64 th = (u64)misc[24 + b];
  const u64* L = keylist + (size_t)b * CAPK;
  for (int i = tid; i < N; i += 1024) {
    u64 k = L[i];
    if ((k >> 38) >= th) {
      u32 pos = atomicAdd(&scnt, 1u);
      if (pos < SELCAP) sk[pos] = k;
    }
  }
  __syncthreads();
  int M = (int)scnt; if (M > SELCAP) M = SELCAP;

  for (int k = 2; k <= SELCAP; k <<= 1) {
    for (int j = k >> 1; j > 0; j >>= 1) {
      __syncthreads();
      for (int i = tid; i < SELCAP; i += 1024) {
        int l = i ^ j;
        if (l > i) {
          u64 a = sk[i], bb = sk[l];
          bool up = ((i & k) == 0);
          bool sw = up ? (a < bb) : (a > bb);
          if (sw) { sk[i] = bb; sk[l] = a; }
        }
      }
    }
  }
  __syncthreads();

  for (int i = tid; i < KTOP; i += 1024) {
    float* o = center + ((size_t)b * KTOP + i) * 5;
    if (i < M) {
      u64 key = sk[i];
      u32 p = (~(u32)key) & 0xFFFFFu;
      float v = convr[(size_t)b * HW + p];
      o[0] = 1.0f;
      o[1] = (float)(p & (W - 1));
      o[2] = (float)(p >> 10);
      o[3] = v;
      o[4] = v;
    } else {
      o[0] = 0.f; o[1] = 0.f; o[2] = 0.f; o[3] = 0.f; o[4] = 0.f;
    }
  }
}

extern "C" void kernel_launch(void* const* d_in, const int* in_sizes, int n_in,
                              void* d_out, int out_size, void* d_ws, size_t ws_size,
                              hipStream_t stream) {
  const float* in  = (const float*)d_in[0];
  const float* wc  = (const float*)d_in[1];
  const float* wsw = (const float*)d_in[2];

  float* out0   = (float*)d_out;                     // (8,3,1024,1024)
  float* center = out0 + (size_t)BATCH * 3 * HW;     // (8,2048,5)
  float* convr  = center + (size_t)BATCH * KTOP * 5; // (8,1,1024,1024)

  char* w = (char*)d_ws;
  u32* misc      = (u32*)(w + OFF_MISC);
  u32* passlist  = (u32*)(w + OFF_PASS);
  u32* checklist = (u32*)(w + OFF_CHK);
  u64* keylist   = (u64*)(w + OFF_KEY);

  hipMemsetAsync(misc, 0, 128, stream);

  conv32_kernel<<<NPIX / 256, 256, 0, stream>>>(in, wc, wsw, out0, convr);
  screen_kernel<<<NPIX / 256, 256, 0, stream>>>(convr, passlist, checklist, misc);
  keygen_kernel<<<1024, 256, 0, stream>>>(in, wc, wsw, passlist, misc, keylist);
  recheck_kernel<<<2048, 256, 0, stream>>>(in, wc, wsw, checklist, misc, keylist);
  select_kernel<<<BATCH, 1024, 0, stream>>>(keylist, misc);
  sort_out_kernel<<<BATCH, 1024, 0, stream>>>(keylist, misc, convr, center);
}

// Round 7
// 3123.256 us; speedup vs baseline: 2.6108x; 2.6108x over previous
//
#include <hip/hip_runtime.h>
#include <cstdint>

typedef unsigned int u32;
typedef unsigned long long u64;

#define BATCH 8
#define H 1024
#define W 1024
#define HW (H*W)
#define NPIX (BATCH*HW)
#define KTOP 2048
#define NBIN 8192
#define KEYCAP 8192
#define CAPP 131072
#define CAPC 65536
#define TARGET 2080

// screen margins: hard f32-vs-f64 error bound ~4.6e-4 (9-sum pair), ~1.4e-5 (single val)
#define D9 1e-3f
#define DV 1e-4f

// ws layout (bytes); [0, OFF_PASS) memset to 0 each launch
#define OFF_MISC 0                          // u32: pass[0..8) chk[8..16) kcnt[16..24) cut[24..32)
#define OFF_HIST 4096                       // u32[8][NBIN] = 256 KB
#define OFF_PASS (OFF_HIST + BATCH*NBIN*4)
#define OFF_CHK  (OFF_PASS + BATCH*CAPP*4)
#define OFF_KEY  (OFF_CHK  + BATCH*CAPC*4)

// ---------------- f64 dilated conv + relu (IDENTICAL to green rounds 3-6) ----------------
__device__ __forceinline__ double conv_resp_f64(
    const float* __restrict__ in, const float* __restrict__ wc,
    const float* __restrict__ wsw, int b, int y, int x)
{
  const float* base = in + (size_t)b * 3 * HW;
  const float* Sp = base;
  const float* Cp = base + HW;
  double resp = 0.0;
  const int dil[3] = {1, 4, 16};
  #pragma unroll
  for (int di = 0; di < 3; ++di) {
    int d = dil[di];
    double ac = 0.0, as = 0.0;
    #pragma unroll
    for (int ky = 0; ky < 3; ++ky) {
      int yy = y + (ky - 1) * d;
      bool yok = ((unsigned)yy < (unsigned)H);
      #pragma unroll
      for (int kx = 0; kx < 3; ++kx) {
        int xx = x + (kx - 1) * d;
        bool ok = yok && ((unsigned)xx < (unsigned)W);
        double a  = ok ? (double)Cp[yy * W + xx] : 0.0;
        double s2 = ok ? (double)Sp[yy * W + xx] : 0.0;
        ac = fma(a,  (double)wc[di * 9 + ky * 3 + kx], ac);
        as = fma(s2, (double)wsw[di * 9 + ky * 3 + kx], as);
      }
    }
    resp += ac;
    resp += as;
  }
  return resp > 0.0 ? resp : 0.0;
}

__device__ __forceinline__ u64 make_key(double val, int p) {
  u64 dbits = __double_as_longlong(val);
  return (dbits & ~0xFFFFFull) | (u64)((~(u32)p) & 0xFFFFFu);
}

// ---------------- f32 conv (guarded / interior) ----------------
template<bool GUARD>
__device__ __forceinline__ float conv_f32(
    const float* __restrict__ Sp, const float* __restrict__ Cp,
    const float* __restrict__ wc, const float* __restrict__ wsw, int y, int x)
{
  float resp = 0.f;
  #pragma unroll
  for (int di = 0; di < 3; ++di) {
    const int d = (di == 0) ? 1 : (di == 1) ? 4 : 16;
    float ac = 0.f, as = 0.f;
    #pragma unroll
    for (int ky = 0; ky < 3; ++ky) {
      int yy = y + (ky - 1) * d;
      bool yok = !GUARD || ((unsigned)yy < (unsigned)H);
      #pragma unroll
      for (int kx = 0; kx < 3; ++kx) {
        int xx = x + (kx - 1) * d;
        bool ok = yok && (!GUARD || ((unsigned)xx < (unsigned)W));
        float a  = ok ? Cp[yy * W + xx] : 0.f;
        float s2 = ok ? Sp[yy * W + xx] : 0.f;
        ac = fmaf(a,  wc[di * 9 + ky * 3 + kx], ac);
        as = fmaf(s2, wsw[di * 9 + ky * 3 + kx], as);
      }
    }
    resp += ac;
    resp += as;
  }
  return resp;
}

// ---------------- kernel 1: elementwise outputs + f32 conv ----------------
__global__ __launch_bounds__(256) void conv32_kernel(
    const float* __restrict__ in, const float* __restrict__ wc,
    const float* __restrict__ wsw, float* __restrict__ out0,
    float* __restrict__ convr)
{
  int gid = blockIdx.x * 256 + threadIdx.x;
  int b = gid >> 20;
  int p = gid & (HW - 1);
  int y = p >> 10;
  int x = p & (W - 1);

  const float* base = in + (size_t)b * 3 * HW;
  const float* Sp = base;
  const float* Cp = base + HW;
  float sv = Sp[p];
  float cv = Cp[p];
  float rv = base[2 * HW + p];
  float* ob = out0 + (size_t)b * 3 * HW;
  ob[p] = sv;
  ob[HW + p] = cv;
  ob[2 * HW + p] = expf(rv) - 1.0f;

  bool interior = (x >= 16) && (x <= W - 17) && (y >= 16) && (y <= H - 17);
  float r = interior ? conv_f32<false>(Sp, Cp, wc, wsw, y, x)
                     : conv_f32<true >(Sp, Cp, wc, wsw, y, x);
  convr[(size_t)b * HW + p] = fmaxf(r, 0.f);
}

// ---------------- kernel 2: f32 margin screen -> passlist/hist/checklist ----------------
__global__ __launch_bounds__(256) void screen_kernel(
    const float* __restrict__ convr, u32* __restrict__ passlist,
    u32* __restrict__ checklist, u32* __restrict__ hist, u32* __restrict__ misc)
{
  int gid = blockIdx.x * 256 + threadIdx.x;
  int b = gid >> 20;
  int p = gid & (HW - 1);
  int y = p >> 10;
  int x = p & (W - 1);
  if (y < 5 || y > H - 6 || x < 5 || x > W - 6) return;

  const float* c0 = convr + (size_t)b * HW + p - 2 * W - 2;
  float cs0[5], cs1[5], cs2[5], val = 0.f;
  #pragma unroll
  for (int j = 0; j < 5; ++j) {
    float v0 = c0[j];
    float v1 = c0[W + j];
    float v2 = c0[2 * W + j];
    float v3 = c0[3 * W + j];
    float v4 = c0[4 * W + j];
    cs0[j] = v0 + v1 + v2;
    cs1[j] = v1 + v2 + v3;
    cs2[j] = v2 + v3 + v4;
    if (j == 2) val = v2;
  }
  float sc9 = cs1[1] + cs1[2] + cs1[3];
  float n00 = cs0[0] + cs0[1] + cs0[2], n01 = cs0[1] + cs0[2] + cs0[3], n02 = cs0[2] + cs0[3] + cs0[4];
  float n10 = cs1[0] + cs1[1] + cs1[2], n12 = cs1[2] + cs1[3] + cs1[4];
  float n20 = cs2[0] + cs2[1] + cs2[2], n21 = cs2[1] + cs2[2] + cs2[3], n22 = cs2[2] + cs2[3] + cs2[4];
  float m9 = fmaxf(fmaxf(fmaxf(n00, n01), fmaxf(n02, n10)),
                   fmaxf(fmaxf(n12, n20), fmaxf(n21, n22)));

  if ((sc9 < 0.9f - D9) || (sc9 < m9 - D9) || (val < 0.1f - DV)) return;

  bool pass = (sc9 > 0.9f + D9) && (sc9 >= m9 + D9) && (val > 0.1f + DV);
  if (pass) {
    u32 pos = atomicAdd(&misc[b], 1u);
    if (pos < CAPP) passlist[(size_t)b * CAPP + pos] = (u32)p;
    atomicAdd(&hist[b * NBIN + (__float_as_uint(val) >> 19)], 1u);
  } else {
    u32 pos = atomicAdd(&misc[8 + b], 1u);
    if (pos < CAPC) checklist[(size_t)b * CAPC + pos] = (u32)p;
  }
}

// ---------------- kernel 3: suffix-scan hist -> f32 cut bits (rank TARGET, one bin slack) --
__global__ __launch_bounds__(1024) void cutscan_kernel(
    const u32* __restrict__ hist, u32* __restrict__ misc)
{
  __shared__ u32 sfx[NBIN];
  int b = blockIdx.x;
  int tid = threadIdx.x;
  const u32* h = hist + b * NBIN;
  #pragma unroll
  for (int k = 0; k < 8; ++k) sfx[tid * 8 + k] = h[tid * 8 + k];
  __syncthreads();

  for (int off = 1; off < NBIN; off <<= 1) {
    u32 t[8];
    #pragma unroll
    for (int k = 0; k < 8; ++k) {
      int i = tid * 8 + k;
      t[k] = (i + off < NBIN) ? sfx[i + off] : 0u;
    }
    __syncthreads();
    #pragma unroll
    for (int k = 0; k < 8; ++k) sfx[tid * 8 + k] += t[k];
    __syncthreads();
  }

  if (sfx[0] < TARGET) return;  // cut stays 0 (memset) -> key everything

  #pragma unroll
  for (int k = 0; k < 8; ++k) {
    int i = tid * 8 + k;
    u32 s = sfx[i];
    u32 nxt = (i + 1 < NBIN) ? sfx[i + 1] : 0u;
    if (s >= TARGET && nxt < TARGET) {
      u32 cutbin = (i > 0) ? (u32)(i - 1) : 0u;   // one-bin slack below rank-TARGET bin
      misc[24 + b] = cutbin << 19;
    }
  }
}

// ---------------- kernel 4: exact f64 keys for pass-peaks above cut ----------------
__global__ __launch_bounds__(256) void keygen_kernel(
    const float* __restrict__ in, const float* __restrict__ wc,
    const float* __restrict__ wsw, const float* __restrict__ convr,
    const u32* __restrict__ passlist, u32* __restrict__ misc, u64* __restrict__ keybuf)
{
  int gtid = blockIdx.x * 256 + threadIdx.x;
  int gsz = gridDim.x * 256;
  for (int b = 0; b < BATCH; ++b) {
    int np = (int)min(misc[b], (u32)CAPP);
    u32 cutb = misc[24 + b];
    for (int i = gtid; i < np; i += gsz) {
      int p = (int)passlist[(size_t)b * CAPP + i];
      float fv = convr[(size_t)b * HW + p];
      if (__float_as_uint(fv) < cutb) continue;
      double v = conv_resp_f64(in, wc, wsw, b, p >> 10, p & (W - 1));
      u32 pos = atomicAdd(&misc[16 + b], 1u);
      if (pos < KEYCAP) keybuf[(size_t)b * KEYCAP + pos] = make_key(v, p);
    }
  }
}

// ---------------- kernel 5: exact f64 recheck, one wave per uncertain pixel ----------------
__global__ __launch_bounds__(256) void recheck_kernel(
    const float* __restrict__ in, const float* __restrict__ wc,
    const float* __restrict__ wsw, const float* __restrict__ convr,
    const u32* __restrict__ checklist, u32* __restrict__ misc, u64* __restrict__ keybuf)
{
  int wid = (blockIdx.x * 256 + threadIdx.x) >> 6;
  int lane = threadIdx.x & 63;
  int nw = (gridDim.x * 256) >> 6;

  for (int b = 0; b < BATCH; ++b) {
    int nc = (int)min(misc[8 + b], (u32)CAPC);
    u32 cutb = misc[24 + b];
    for (int i = wid; i < nc; i += nw) {
      int p = (int)checklist[(size_t)b * CAPC + i];
      int y = p >> 10, x = p & (W - 1);

      double v = 0.0;
      if (lane < 25)
        v = conv_resp_f64(in, wc, wsw, b, y + lane / 5 - 2, x + lane % 5 - 2);

      double c[25];
      #pragma unroll
      for (int k = 0; k < 25; ++k) c[k] = __shfl(v, k);

      double cs0[5], cs1[5], cs2[5];
      #pragma unroll
      for (int j = 0; j < 5; ++j) {
        cs0[j] = c[0 + j] + c[5 + j] + c[10 + j];
        cs1[j] = c[5 + j] + c[10 + j] + c[15 + j];
        cs2[j] = c[10 + j] + c[15 + j] + c[20 + j];
      }
      double val = c[12];

      double sc = (cs1[1] + cs1[2] + cs1[3]) * (1.0 / 9.0);
      if (!(sc > 0.1)) continue;
      bool pk = true;
      #pragma unroll
      for (int j = 0; j < 3; ++j) {
        pk = pk && (sc >= (cs0[j] + cs0[j + 1] + cs0[j + 2]) * (1.0 / 9.0));
        pk = pk && (sc >= (cs2[j] + cs2[j + 1] + cs2[j + 2]) * (1.0 / 9.0));
      }
      pk = pk && (sc >= (cs1[0] + cs1[1] + cs1[2]) * (1.0 / 9.0));
      pk = pk && (sc >= (cs1[2] + cs1[3] + cs1[4]) * (1.0 / 9.0));
      if (!pk) continue;
      if (!(val > 0.1)) continue;

      float fv = convr[(size_t)b * HW + p];
      if (__float_as_uint(fv) < cutb) continue;

      if (lane == 0) {
        u32 pos = atomicAdd(&misc[16 + b], 1u);
        if (pos < KEYCAP) keybuf[(size_t)b * KEYCAP + pos] = make_key(val, p);
      }
    }
  }
}

// ---------------- kernel 6: per-batch bitonic sort of keyed set -> center_pred ----------
__global__ __launch_bounds__(1024) void sort_out_kernel(
    const u64* __restrict__ keybuf, const u32* __restrict__ misc,
    const float* __restrict__ convr, float* __restrict__ center)
{
  __shared__ u64 sk[KEYCAP];
  int b = blockIdx.x;
  int tid = threadIdx.x;
  int M = (int)min(misc[16 + b], (u32)KEYCAP);
  const u64* kb = keybuf + (size_t)b * KEYCAP;
  for (int i = tid; i < KEYCAP; i += 1024) sk[i] = (i < M) ? kb[i] : 0ULL;

  for (int k = 2; k <= KEYCAP; k <<= 1) {
    for (int j = k >> 1; j > 0; j >>= 1) {
      __syncthreads();
      for (int i = tid; i < KEYCAP; i += 1024) {
        int l = i ^ j;
        if (l > i) {
          u64 a = sk[i], bb = sk[l];
          bool up = ((i & k) == 0);
          bool sw = up ? (a < bb) : (a > bb);
          if (sw) { sk[i] = bb; sk[l] = a; }
        }
      }
    }
  }
  __syncthreads();

  for (int i = tid; i < KTOP; i += 1024) {
    float* o = center + ((size_t)b * KTOP + i) * 5;
    if (i < M) {
      u64 key = sk[i];
      u32 p = (~(u32)key) & 0xFFFFFu;
      float v = convr[(size_t)b * HW + p];
      o[0] = 1.0f;
      o[1] = (float)(p & (W - 1));
      o[2] = (float)(p >> 10);
      o[3] = v;
      o[4] = v;
    } else {
      o[0] = 0.f; o[1] = 0.f; o[2] = 0.f; o[3] = 0.f; o[4] = 0.f;
    }
  }
}

extern "C" void kernel_launch(void* const* d_in, const int* in_sizes, int n_in,
                              void* d_out, int out_size, void* d_ws, size_t ws_size,
                              hipStream_t stream) {
  const float* in  = (const float*)d_in[0];
  const float* wc  = (const float*)d_in[1];
  const float* wsw = (const float*)d_in[2];

  float* out0   = (float*)d_out;                     // (8,3,1024,1024)
  float* center = out0 + (size_t)BATCH * 3 * HW;     // (8,2048,5)
  float* convr  = center + (size_t)BATCH * KTOP * 5; // (8,1,1024,1024)

  char* w = (char*)d_ws;
  u32* misc      = (u32*)(w + OFF_MISC);
  u32* hist      = (u32*)(w + OFF_HIST);
  u32* passlist  = (u32*)(w + OFF_PASS);
  u32* checklist = (u32*)(w + OFF_CHK);
  u64* keybuf    = (u64*)(w + OFF_KEY);

  hipMemsetAsync(w, 0, OFF_PASS, stream);  // misc + hist

  conv32_kernel<<<NPIX / 256, 256, 0, stream>>>(in, wc, wsw, out0, convr);
  screen_kernel<<<NPIX / 256, 256, 0, stream>>>(convr, passlist, checklist, hist, misc);
  cutscan_kernel<<<BATCH, 1024, 0, stream>>>(hist, misc);
  keygen_kernel<<<2048, 256, 0, stream>>>(in, wc, wsw, convr, passlist, misc, keybuf);
  recheck_kernel<<<1024, 256, 0, stream>>>(in, wc, wsw, convr, checklist, misc, keybuf);
  sort_out_kernel<<<BATCH, 1024, 0, stream>>>(keybuf, misc, convr, center);
}